// Round 6
// baseline (825.157 us; speedup 1.0000x reference)
//
#include <hip/hip_runtime.h>
#include <hip/hip_fp16.h>

#define BB 512
#define TT 512
#define EE 100
#define HH 40
#define GG 120   // 3*HH
#define TC 64    // timesteps per chunk
#define NC 8     // chunks
#define X1S 96   // layer-1 input row stride (80 valid + 16 pad, 3 k-steps of 32)

typedef _Float16 h2_t __attribute__((ext_vector_type(2)));
typedef _Float16 h8_t __attribute__((ext_vector_type(8)));
typedef float    f4_t __attribute__((ext_vector_type(4)));

__device__ __forceinline__ float fdot2_(h2_t a, h2_t b, float c) {
    return __builtin_amdgcn_fdot2(a, b, c, false);
}
__device__ __forceinline__ h2_t pack2_(float x, float y) {
    h2_t r; r[0] = (_Float16)x; r[1] = (_Float16)y; return r;
}
__device__ __forceinline__ float sigmoid_(float x) {
    return __builtin_amdgcn_rcpf(1.0f + __expf(-x));
}
__device__ __forceinline__ float tanhfast_(float x) {
    return 1.0f - 2.0f * __builtin_amdgcn_rcpf(__expf(2.0f * x) + 1.0f);
}

// Round-15 model: r5 (-85us) removed GEMM LDS + forced Whh residency; all
// fused dispatches now < 42us and the scan remains the pole at ~1050cy/step
// vs a ~500cy dep chain (LDS h-broadcast ~250 + 60 fdot2 issue ~120 + nonlin
// ~80). One scan wave per SIMD has nothing to hide its own stalls under.
// Fix: TWO chains per wave, interleaved: pair (dir,b) with (dir,b+256) --
// same dir => SAME Whh register image (60 VGPRs shared), same biases, same
// chunk geometry. While A waits on its LDS round-trip, B's dots issue.
// Expected per-step ~260cy; scan waves halve to 512 (2/CU).
// Per-chain [sBeg,sEnd) guards are wave-uniform scalar branches; prefetch is
// unconditional with clamped (address-safe) indices.
template<int K, bool GATHER>
__global__ __launch_bounds__(256, 2) void fused_kernel(
    const int cg, const int cs, const int nScan,
    const int* __restrict__ text, const __half* __restrict__ emb16,
    const __half* __restrict__ Xh,
    const _Float16* __restrict__ Wt,
    const float* __restrict__ bf, const float* __restrict__ bb,
    __half* __restrict__ gxW, const __half* __restrict__ gxR,
    const _Float16* __restrict__ WhhL,
    const float* __restrict__ bhhF, const float* __restrict__ bhhB,
    const int* __restrict__ lens,
    __half* __restrict__ out0,
    float* __restrict__ hcar, float* __restrict__ hlast,
    float* __restrict__ sumb, float* __restrict__ maxb)
{
    constexpr int KS = (K == 100) ? 4 : 3;       // k-steps of 32
    __shared__ __align__(16) _Float16 hsh[4][2][48];
    const int tid = threadIdx.x;

    if ((int)blockIdx.x < nScan) {
        // ===== scan: one wave = TWO (b, b+256) chains, same dir =====
        __builtin_amdgcn_s_setprio(3);
        const int wave = tid >> 6, j = tid & 63;
        if (j >= HH) return;
        const int p   = blockIdx.x * 4 + wave;   // 0..511 pair index
        const int dir = p >> 8;
        const int bA  = p & 255;
        const int bB  = bA + 256;
        const float* bhh = dir ? bhhB : bhhF;

        // Whh rows {j,40+j,80+j} fp16 in 15 h8 registers, forced resident
        h8_t R0,R1,R2,R3,R4, Z0,Z1,Z2,Z3,Z4, N0,N1,N2,N3,N4;
        {
            const _Float16* wr = WhhL + (size_t)dir * 4800;
            const h8_t* pr = (const h8_t*)(wr + (size_t)j * 40);
            const h8_t* pz = (const h8_t*)(wr + (size_t)(40 + j) * 40);
            const h8_t* pn = (const h8_t*)(wr + (size_t)(80 + j) * 40);
            R0=pr[0]; R1=pr[1]; R2=pr[2]; R3=pr[3]; R4=pr[4];
            Z0=pz[0]; Z1=pz[1]; Z2=pz[2]; Z3=pz[3]; Z4=pz[4];
            N0=pn[0]; N1=pn[1]; N2=pn[2]; N3=pn[3]; N4=pn[4];
        }
        asm volatile("" : "+v"(R0),"+v"(R1),"+v"(R2),"+v"(R3),"+v"(R4),
                          "+v"(Z0),"+v"(Z1),"+v"(Z2),"+v"(Z3),"+v"(Z4),
                          "+v"(N0),"+v"(N1),"+v"(N2),"+v"(N3),"+v"(N4));
        const float br = bhh[j], bz = bhh[HH + j], bn = bhh[2*HH + j];
        const int chunk = dir ? (NC - 1 - cs) : cs;
        const int tbase = chunk * TC;

        const int lenA = lens[bA], lenB = lens[bB];
        int sBegA, sEndA, sBegB, sEndB;
        if (dir == 0) {
            sBegA = 0; sEndA = min(TC, max(0, lenA - tbase));
            sBegB = 0; sEndB = min(TC, max(0, lenB - tbase));
        } else {
            sBegA = max(0, tbase + TC - lenA); sEndA = TC;
            sBegB = max(0, tbase + TC - lenB); sEndB = TC;
        }

        float hA = (cs == 0) ? 0.0f : hcar[(size_t)(dir * BB + bA) * HH + j];
        float hB = (cs == 0) ? 0.0f : hcar[(size_t)(dir * BB + bB) * HH + j];
        hsh[wave][0][j] = (_Float16)hA;
        hsh[wave][1][j] = (_Float16)hB;
        float psA = 0.0f, pmA = -3.4e38f, psB = 0.0f, pmB = -3.4e38f;
        const size_t gxRowA = ((size_t)dir * BB + bA) * TC;
        const size_t gxRowB = ((size_t)dir * BB + bB) * TC;
        const float4* h4A = (const float4*)hsh[wave][0];
        const float4* h4B = (const float4*)hsh[wave][1];

        struct G3 { __half r, z, n; };
        auto ldg3 = [&](size_t gxRow, int sc, int sEnd) -> G3 {
            const int scc = max(0, min(sc, sEnd - 1));   // address-safe clamp
            const int tl = dir ? (TC - 1 - scc) : scc;
            const __half* gp = gxR + (gxRow + tl) * GG;
            G3 g; g.r = gp[j]; g.z = gp[HH + j]; g.n = gp[2*HH + j];
            return g;
        };
#define SL(V,i) __builtin_shufflevector(V, V, 2*(i), 2*(i)+1)
#define DOTQ(Rq,Zq,Nq,U) \
        r0 = fdot2_(SL(Rq,0), U.hh[0], r0); \
        z0 = fdot2_(SL(Zq,0), U.hh[0], z0); \
        n0 = fdot2_(SL(Nq,0), U.hh[0], n0); \
        r1 = fdot2_(SL(Rq,1), U.hh[1], r1); \
        z1 = fdot2_(SL(Zq,1), U.hh[1], z1); \
        n1 = fdot2_(SL(Nq,1), U.hh[1], n1); \
        r0 = fdot2_(SL(Rq,2), U.hh[2], r0); \
        z0 = fdot2_(SL(Zq,2), U.hh[2], z0); \
        n0 = fdot2_(SL(Nq,2), U.hh[2], n0); \
        r1 = fdot2_(SL(Rq,3), U.hh[3], r1); \
        z1 = fdot2_(SL(Zq,3), U.hh[3], z1); \
        n1 = fdot2_(SL(Nq,3), U.hh[3], n1);

        // one GRU step of one chain; all-in-register except hsh broadcast
        auto stepX = [&](int s, G3 g, float& h, _Float16* hrow,
                         const float4* h4, int bX, float& psum, float& pmax) {
            const int tloc = dir ? (TC - 1 - s) : s;
            float r0 = br, r1 = 0.f, z0 = bz, z1 = 0.f, n0 = bn, n1 = 0.f;
            union { float4 f; h2_t hh[4]; } u0, u1, u2, u3, u4;
            u0.f = h4[0]; u1.f = h4[1]; u2.f = h4[2]; u3.f = h4[3]; u4.f = h4[4];
            DOTQ(R0,Z0,N0,u0)
            DOTQ(R1,Z1,N1,u1)
            DOTQ(R2,Z2,N2,u2)
            DOTQ(R3,Z3,N3,u3)
            DOTQ(R4,Z4,N4,u4)
            const float rr = sigmoid_(__half2float(g.r) + r0 + r1);
            const float zz = sigmoid_(__half2float(g.z) + z0 + z1);
            const float nn = tanhfast_(__half2float(g.n) + rr * (n0 + n1));
            const float hn = (1.0f - zz) * nn + zz * h;
            h = hn;
            hrow[j] = (_Float16)hn;
            if (GATHER) {
                const int t = tbase + tloc;
                out0[((size_t)bX * TT + t) * X1S + dir*HH + j] = __float2half(hn);
            } else {
                psum += hn;
                pmax = fmaxf(pmax, hn);
            }
        };

        const int s0 = min(sBegA, sBegB);
        const int s1 = max(sEndA, sEndB);
        G3 a0 = ldg3(gxRowA, s0,     sEndA);
        G3 a1 = ldg3(gxRowA, s0 + 1, sEndA);
        G3 b0 = ldg3(gxRowB, s0,     sEndB);
        G3 b1 = ldg3(gxRowB, s0 + 1, sEndB);
        int s = s0;
        for (; s + 2 <= s1; s += 2) {
            // sub-step s: refill slot0 for s+2, execute both chains
            G3 na = ldg3(gxRowA, s + 2, sEndA);
            G3 nb = ldg3(gxRowB, s + 2, sEndB);
            if (s >= sBegA && s < sEndA)
                stepX(s, a0, hA, hsh[wave][0], h4A, bA, psA, pmA);
            if (s >= sBegB && s < sEndB)
                stepX(s, b0, hB, hsh[wave][1], h4B, bB, psB, pmB);
            a0 = na; b0 = nb;
            // sub-step s+1: refill slot1 for s+3
            na = ldg3(gxRowA, s + 3, sEndA);
            nb = ldg3(gxRowB, s + 3, sEndB);
            if (s + 1 >= sBegA && s + 1 < sEndA)
                stepX(s + 1, a1, hA, hsh[wave][0], h4A, bA, psA, pmA);
            if (s + 1 >= sBegB && s + 1 < sEndB)
                stepX(s + 1, b1, hB, hsh[wave][1], h4B, bB, psB, pmB);
            a1 = na; b1 = nb;
        }
        if (s < s1) {   // odd tail: parity of s-s0 is even -> slot0
            if (s >= sBegA && s < sEndA)
                stepX(s, a0, hA, hsh[wave][0], h4A, bA, psA, pmA);
            if (s >= sBegB && s < sEndB)
                stepX(s, b0, hB, hsh[wave][1], h4B, bB, psB, pmB);
        }

        hcar[(size_t)(dir * BB + bA) * HH + j] = hA;
        hcar[(size_t)(dir * BB + bB) * HH + j] = hB;
        const int layer = GATHER ? 0 : 1;
        if (cs == NC - 1) {
            hlast[((size_t)(layer * 2 + dir) * BB + bA) * HH + j] = hA;
            hlast[((size_t)(layer * 2 + dir) * BB + bB) * HH + j] = hB;
        }
        if (!GATHER) {
            const size_t piA = (size_t)bA * (2*HH) + dir*HH + j;
            const size_t piB = (size_t)bB * (2*HH) + dir*HH + j;
            if (cs == 0) { sumb[piA] = psA;  maxb[piA] = pmA;
                           sumb[piB] = psB;  maxb[piB] = pmB; }
            else         { sumb[piA] += psA; maxb[piA] = fmaxf(maxb[piA], pmA);
                           sumb[piB] += psB; maxb[piB] = fmaxf(maxb[piB], pmB); }
        }
        return;
    }

    // ============ gemm (MFMA f16, B straight from L2, no LDS) ============
    __builtin_amdgcn_s_setprio(0);
    const int gid = blockIdx.x - nScan;
    const int b   = gid & (BB - 1);
    const int dir = gid >> 9;
    const int chunk = dir ? (NC - 1 - cg) : cg;
    const int tbase = chunk * TC;
    if (tbase >= lens[b]) return;   // tile fully past len: gx never read
    const float* bias = dir ? bb : bf;
    const _Float16* Wg = Wt + (size_t)dir * (KS * 8 * 64 * 8);

    // A gather: lane l -> row = l&15 of wave's 16-row stripe, k-chunk (l>>4)*8
    const int w = tid >> 6, l = tid & 63;
    const int row = l & 15, kq = l >> 4;
    const int t0 = tbase + w * 16 + row;
    h8_t A[4];
    if (GATHER) {
        const int tok = text[b * TT + t0];
        const _Float16* ap = (const _Float16*)emb16 + (size_t)tok * 128 + kq * 8;
        #pragma unroll
        for (int ks = 0; ks < KS; ++ks) A[ks] = *(const h8_t*)(ap + ks * 32);
    } else {
        const _Float16* ap = (const _Float16*)Xh + ((size_t)b * TT + t0) * X1S + kq * 8;
        #pragma unroll
        for (int ks = 0; ks < KS; ++ks) A[ks] = *(const h8_t*)(ap + ks * 32);
    }

    f4_t acc[8] = {};
    #pragma unroll
    for (int ks = 0; ks < KS; ++ks)
        #pragma unroll
        for (int f = 0; f < 8; ++f) {
            const h8_t Bf = *(const h8_t*)(Wg + ((size_t)(ks * 8 + f) * 64 + l) * 8);
            acc[f] = __builtin_amdgcn_mfma_f32_16x16x32_f16(A[ks], Bf, acc[f], 0, 0, 0);
        }

    // epilogue: D[m=(l>>4)*4+reg][n=l&15]; per-element fp16 stores
    const size_t rowB = ((size_t)dir * BB + b) * TC;
    const int gb = l & 15, rq = l >> 4;
    #pragma unroll
    for (int f = 0; f < 8; ++f) {
        const int gate = f * 16 + gb;
        if (gate < GG) {
            const float bv = bias[gate];
            #pragma unroll
            for (int r = 0; r < 4; ++r) {
                const int tloc = w * 16 + rq * 4 + r;
                gxW[(rowB + tloc) * GG + gate] = __float2half(acc[f][r] + bv);
            }
        }
    }
}

// Precompute fp16 tables:
//  emb16 [50000][128] zero-padded; Wt16 = exact B-fragment images:
//  L0 [dir][ks<4][f<8][l<64][i<8], L1 [dir][ks<3][f<8][l<64][i<8];
//  Whh16 fp16 row-major [lay*2+dir][120][40]; plus zero out0 pad columns.
#define NE2 (50000 * 64)        // h2 units of padded emb16
#define NW0 (2*4*8*64)          // 4096 h8 units
#define NW1 (2*3*8*64)          // 3072 h8 units
#define NHH (4*120*20)          // 9600 h2 units
#define NP0 (BB*TT*8)           // h2 units of out0 pad (16 halfs/row)
__global__ __launch_bounds__(256) void prep_kernel(
    const float* __restrict__ emb,
    const float* __restrict__ Wih0f, const float* __restrict__ Wih0b,
    const float* __restrict__ Wih1f, const float* __restrict__ Wih1b,
    const float* __restrict__ Whh0f, const float* __restrict__ Whh0b,
    const float* __restrict__ Whh1f, const float* __restrict__ Whh1b,
    __half* __restrict__ emb16, _Float16* __restrict__ Wt16,
    _Float16* __restrict__ Whh16, __half* __restrict__ out0)
{
    const int gid = blockIdx.x * 256 + threadIdx.x;
    if (gid < NE2) {
        const int v = gid >> 6, q2 = gid & 63;
        const int k0 = q2 * 2;
        float x0 = 0.f, x1 = 0.f;
        if (k0 < EE) { x0 = emb[(size_t)v * EE + k0]; x1 = emb[(size_t)v * EE + k0 + 1]; }
        ((h2_t*)emb16)[(size_t)v * 64 + q2] = pack2_(x0, x1);
        return;
    }
    int e = gid - NE2;
    if (e < NP0) {              // zero out0 pad columns (halfs 80..95 per row)
        const int row = e >> 3, q = e & 7;
        ((h2_t*)out0)[(size_t)row * 48 + 40 + q] = pack2_(0.f, 0.f);
        return;
    }
    e -= NP0;
    if (e < NW0) {              // layer0 B-fragments, K=100 (pad 128)
        const int l = e & 63, f = (e >> 6) & 7, ks = (e >> 9) & 3, dir = e >> 11;
        const float* W = dir ? Wih0b : Wih0f;
        const int col = f * 16 + (l & 15);
        const int kb  = ks * 32 + (l >> 4) * 8;
        _Float16* dst = Wt16 + (size_t)e * 8;
        #pragma unroll
        for (int i = 0; i < 8; ++i) {
            const int k = kb + i;
            dst[i] = (_Float16)((col < GG && k < EE) ? W[(size_t)col * EE + k] : 0.f);
        }
        return;
    }
    e -= NW0;
    if (e < NW1) {              // layer1 B-fragments, K=80 (pad 96)
        const int l = e & 63, f = (e >> 6) & 7;
        const int t = e >> 9;               // 0..5 = dir*3 + ks
        const int ks = t % 3, dir = t / 3;
        const float* W = dir ? Wih1b : Wih1f;
        const int col = f * 16 + (l & 15);
        const int kb  = ks * 32 + (l >> 4) * 8;
        _Float16* dst = Wt16 + (size_t)(NW0 + e) * 8;
        #pragma unroll
        for (int i = 0; i < 8; ++i) {
            const int k = kb + i;
            dst[i] = (_Float16)((col < GG && k < 2*HH) ? W[(size_t)col * (2*HH) + k] : 0.f);
        }
        return;
    }
    e -= NW1;
    if (e < NHH) {              // Whh fp16, 4 x [120][40]
        const int ld = e / 2400, rem = e - ld * 2400;
        const int row2 = rem / 20, kk = rem - row2 * 20;
        const float* W = (ld == 0) ? Whh0f : (ld == 1) ? Whh0b
                       : (ld == 2) ? Whh1f : Whh1b;
        ((h2_t*)Whh16)[e] = pack2_(W[row2*HH + 2*kk], W[row2*HH + 2*kk + 1]);
    }
}

// pool_cat = [hb1, hf1, hb0, hf0, avg(80), max(80)] -> fc1(128) -> lrelu -> fc2(1)
__global__ __launch_bounds__(128) void fc_kernel(
    const float* __restrict__ hlast, const float* __restrict__ sumb,
    const float* __restrict__ maxb, const int* __restrict__ lens,
    const float* __restrict__ fc1W, const float* __restrict__ fc1b,
    const float* __restrict__ fc2W, const float* __restrict__ fc2b,
    float* __restrict__ out)
{
    __shared__ float pool[8 * HH];
    __shared__ float red[128];
    const int b = blockIdx.x, tid = threadIdx.x;
    if (tid < HH) {
        pool[tid]        = hlast[(size_t)(3*BB + b) * HH + tid]; // hb1
        pool[HH + tid]   = hlast[(size_t)(2*BB + b) * HH + tid]; // hf1
        pool[2*HH + tid] = hlast[(size_t)(1*BB + b) * HH + tid]; // hb0
        pool[3*HH + tid] = hlast[(size_t)(0*BB + b) * HH + tid]; // hf0
    }
    const float invLen = 1.0f / (float)lens[b];
    if (tid < 2*HH) {
        pool[4*HH + tid] = sumb[(size_t)b * 2*HH + tid] * invLen;
        pool[6*HH + tid] = maxb[(size_t)b * 2*HH + tid];
    }
    __syncthreads();
    float acc = fc1b[tid];
    for (int k = 0; k < 8*HH; ++k)
        acc = fmaf(pool[k], fc1W[(size_t)tid * (8*HH) + k], acc);
    float v = (acc >= 0.0f) ? acc : 0.01f * acc;
    red[tid] = v * fc2W[tid];
    __syncthreads();
    for (int s = 64; s > 0; s >>= 1) {
        if (tid < s) red[tid] += red[tid + s];
        __syncthreads();
    }
    if (tid == 0) out[b] = red[0] + fc2b[0];
}

extern "C" void kernel_launch(void* const* d_in, const int* in_sizes, int n_in,
                              void* d_out, int out_size, void* d_ws, size_t ws_size,
                              hipStream_t stream) {
    const int*   text  = (const int*)d_in[0];
    const int*   lens  = (const int*)d_in[1];
    const float* emb   = (const float*)d_in[2];
    const float* Wih0f = (const float*)d_in[3];
    const float* Whh0f = (const float*)d_in[4];
    const float* bih0f = (const float*)d_in[5];
    const float* bhh0f = (const float*)d_in[6];
    const float* Wih0b = (const float*)d_in[7];
    const float* Whh0b = (const float*)d_in[8];
    const float* bih0b = (const float*)d_in[9];
    const float* bhh0b = (const float*)d_in[10];
    const float* Wih1f = (const float*)d_in[11];
    const float* Whh1f = (const float*)d_in[12];
    const float* bih1f = (const float*)d_in[13];
    const float* bhh1f = (const float*)d_in[14];
    const float* Wih1b = (const float*)d_in[15];
    const float* Whh1b = (const float*)d_in[16];
    const float* bih1b = (const float*)d_in[17];
    const float* bhh1b = (const float*)d_in[18];
    const float* fc1W  = (const float*)d_in[19];
    const float* fc1b  = (const float*)d_in[20];
    const float* fc2W  = (const float*)d_in[21];
    const float* fc2b  = (const float*)d_in[22];
    float* out = (float*)d_out;

    // ws: gx dbuf fp16 | out0 fp16 (stride 96) | small | fp16 tables
    char* p = (char*)d_ws;
    const size_t gxB = (size_t)2 * BB * TC * GG * sizeof(__half);
    __half* gxb0  = (__half*)p;  p += gxB;
    __half* gxb1  = (__half*)p;  p += gxB;
    __half* out0  = (__half*)p;  p += (size_t)BB * TT * X1S * sizeof(__half);
    float*  hcar  = (float*)p;   p += (size_t)2 * BB * HH * sizeof(float);
    float*  hlast = (float*)p;   p += (size_t)4 * BB * HH * sizeof(float);
    float*  sumb  = (float*)p;   p += (size_t)BB * 2 * HH * sizeof(float);
    float*  maxb  = (float*)p;   p += (size_t)BB * 2 * HH * sizeof(float);
    __half*    emb16 = (__half*)p;    p += (size_t)50000 * 128 * sizeof(__half);
    _Float16*  Wt16  = (_Float16*)p;  p += (size_t)(NW0 + NW1) * 8 * sizeof(_Float16);
    _Float16*  Whh16 = (_Float16*)p;
    __half* gxb[2] = { gxb0, gxb1 };

    const int NG = BB * 2;       // 1024 gemm blocks (b, dir)
    const int NS = 128;          // 512 chain-pairs / 4 waves per block

    // ---- precompute fp16 tables + out0 pad zeroing ----
    {
        const int total = NE2 + NP0 + NW0 + NW1 + NHH;
        prep_kernel<<<(total + 255) / 256, 256, 0, stream>>>(
            emb, Wih0f, Wih0b, Wih1f, Wih1b, Whh0f, Whh0b, Whh1f, Whh1b,
            emb16, Wt16, Whh16, out0);
    }

    // ---- layer 0 ----
    fused_kernel<EE, true><<<NG, 256, 0, stream>>>(0, 0, 0,
        text, emb16, nullptr, Wt16, bih0f, bih0b,
        gxb[0], gxb[0], Whh16, bhh0f, bhh0b,
        lens, out0, hcar, hlast, sumb, maxb);
    for (int ci = 1; ci < NC; ++ci)
        fused_kernel<EE, true><<<NS + NG, 256, 0, stream>>>(ci, ci - 1, NS,
            text, emb16, nullptr, Wt16, bih0f, bih0b,
            gxb[ci & 1], gxb[(ci - 1) & 1], Whh16, bhh0f, bhh0b,
            lens, out0, hcar, hlast, sumb, maxb);
    fused_kernel<EE, true><<<NS, 256, 0, stream>>>(0, NC - 1, NS,
        text, emb16, nullptr, Wt16, bih0f, bih0b,
        gxb[0], gxb[(NC - 1) & 1], Whh16, bhh0f, bhh0b,
        lens, out0, hcar, hlast, sumb, maxb);

    // ---- layer 1 ----
    fused_kernel<2*HH, false><<<NG, 256, 0, stream>>>(0, 0, 0,
        text, emb16, out0, Wt16 + (size_t)NW0 * 8, bih1f, bih1b,
        gxb[0], gxb[0], Whh16 + 9600, bhh1f, bhh1b,
        lens, out0, hcar, hlast, sumb, maxb);
    for (int ci = 1; ci < NC; ++ci)
        fused_kernel<2*HH, false><<<NS + NG, 256, 0, stream>>>(ci, ci - 1, NS,
            text, emb16, out0, Wt16 + (size_t)NW0 * 8, bih1f, bih1b,
            gxb[ci & 1], gxb[(ci - 1) & 1], Whh16 + 9600, bhh1f, bhh1b,
            lens, out0, hcar, hlast, sumb, maxb);
    fused_kernel<2*HH, false><<<NS, 256, 0, stream>>>(0, NC - 1, NS,
        text, emb16, out0, Wt16 + (size_t)NW0 * 8, bih1f, bih1b,
        gxb[0], gxb[(NC - 1) & 1], Whh16 + 9600, bhh1f, bhh1b,
        lens, out0, hcar, hlast, sumb, maxb);

    // ---- head ----
    fc_kernel<<<BB, 128, 0, stream>>>(hlast, sumb, maxb, lens,
        fc1W, fc1b, fc2W, fc2b, out);
}

// Round 8
// 541.205 us; speedup vs baseline: 1.5247x; 1.5247x over previous
//
#include <hip/hip_runtime.h>
#include <hip/hip_fp16.h>

#define BB 512
#define TT 512
#define EE 100
#define HH 40
#define GG 120   // 3*HH
#define TC 64    // timesteps per chunk
#define NC 8     // chunks
#define X1S 96   // layer-1 input row stride (80 valid + 16 pad, 3 k-steps of 32)

typedef _Float16 h2_t __attribute__((ext_vector_type(2)));
typedef _Float16 h8_t __attribute__((ext_vector_type(8)));
typedef float    f4_t __attribute__((ext_vector_type(4)));

__device__ __forceinline__ float fdot2_(h2_t a, h2_t b, float c) {
    return __builtin_amdgcn_fdot2(a, b, c, false);
}
__device__ __forceinline__ h2_t pack2_(float x, float y) {
    h2_t r; r[0] = (_Float16)x; r[1] = (_Float16)y; return r;
}
__device__ __forceinline__ float sigmoid_(float x) {
    return __builtin_amdgcn_rcpf(1.0f + __expf(-x));
}
__device__ __forceinline__ float tanhfast_(float x) {
    return 1.0f - 2.0f * __builtin_amdgcn_rcpf(__expf(2.0f * x) + 1.0f);
}

// Round-17 = round-16 with ONE fix: DPP ctrl 0x111 (row_shr:1, out[i]=in[i-1])
// -> 0x101 (row_shl:1, out[i]=in[i+1]). r7's absmax 0.155 was exactly the
// one-lane-shifted recurrent state this bug produces (pair [h2i, h2i-1]
// instead of [h2i, h2i+1]). Direction verified against the ISA reduction
// idiom: row_shr:1 accumulates lane i-1 into i => row_shl gives i+1.
// Model under test (unchanged): scan step ~1050cy, biggest term = LDS
// h-broadcast round-trip (~300cy). Register broadcast replaces it:
//   cvt f16 -> DPP row_shl:1 -> pack (t<<16)|v -> 20 readlane (even lanes)
//   -> 20 uniform h2 in SGPRs consumed by fdot2 directly. Dep ~25cy.
// Markers: LDS_Block_Size -> 0 (fused), VGPR ~96-112, scan ~15-20us.
template<int K, bool GATHER>
__global__ __launch_bounds__(256, 1) void fused_kernel(
    const int cg, const int cs, const int nScan,
    const int* __restrict__ text, const __half* __restrict__ emb16,
    const __half* __restrict__ Xh,
    const _Float16* __restrict__ Wt,
    const float* __restrict__ bf, const float* __restrict__ bb,
    __half* __restrict__ gxW, const __half* __restrict__ gxR,
    const _Float16* __restrict__ WhhL,
    const float* __restrict__ bhhF, const float* __restrict__ bhhB,
    const int* __restrict__ lens,
    __half* __restrict__ out0,
    float* __restrict__ hcar, float* __restrict__ hlast,
    float* __restrict__ sumb, float* __restrict__ maxb)
{
    constexpr int KS = (K == 100) ? 4 : 3;       // k-steps of 32
    const int tid = threadIdx.x;

    if ((int)blockIdx.x < nScan) {
        // ============ scan: one wave = one (batch,dir) chain ============
        __builtin_amdgcn_s_setprio(3);
        const int wave = tid >> 6, j = tid & 63;
        if (j >= HH) return;
        const int chain = blockIdx.x * 4 + wave;   // 0..1023
        const int dir = chain >> 9;
        const int b   = chain & (BB - 1);
        const float* bhh = dir ? bhhB : bhhF;

        // Whh rows {j,40+j,80+j} fp16 in 15 h8 registers, forced resident
        h8_t R0,R1,R2,R3,R4, Z0,Z1,Z2,Z3,Z4, N0,N1,N2,N3,N4;
        {
            const _Float16* wr = WhhL + (size_t)dir * 4800;
            const h8_t* pr = (const h8_t*)(wr + (size_t)j * 40);
            const h8_t* pz = (const h8_t*)(wr + (size_t)(40 + j) * 40);
            const h8_t* pn = (const h8_t*)(wr + (size_t)(80 + j) * 40);
            R0=pr[0]; R1=pr[1]; R2=pr[2]; R3=pr[3]; R4=pr[4];
            Z0=pz[0]; Z1=pz[1]; Z2=pz[2]; Z3=pz[3]; Z4=pz[4];
            N0=pn[0]; N1=pn[1]; N2=pn[2]; N3=pn[3]; N4=pn[4];
        }
        asm volatile("" : "+v"(R0),"+v"(R1),"+v"(R2),"+v"(R3),"+v"(R4),
                          "+v"(Z0),"+v"(Z1),"+v"(Z2),"+v"(Z3),"+v"(Z4),
                          "+v"(N0),"+v"(N1),"+v"(N2),"+v"(N3),"+v"(N4));
        const float br = bhh[j], bz = bhh[HH + j], bn = bhh[2*HH + j];
        const int len = lens[b];
        const int chunk = dir ? (NC - 1 - cs) : cs;
        const int tbase = chunk * TC;

        // executed step range: all executed steps have t < len
        int sBeg, sEnd;
        if (dir == 0) { sBeg = 0; sEnd = min(TC, max(0, len - tbase)); }
        else          { sBeg = max(0, tbase + TC - len); sEnd = TC; }

        float h = (cs == 0) ? 0.0f : hcar[(size_t)(dir * BB + b) * HH + j];
        float psum = 0.0f, pmax = -3.4e38f;
        const size_t gxRow = ((size_t)dir * BB + b) * TC;

        // 20 uniform h2 broadcast registers (live in SGPRs via readlane)
        h2_t H0{},H1{},H2{},H3{},H4{},H5{},H6{},H7{},H8{},H9{},
             H10{},H11{},H12{},H13{},H14{},H15{},H16{},H17{},H18{},H19{};
#define RDL(L) __builtin_bit_cast(h2_t, __builtin_amdgcn_readlane(pk_, (L)))
#define REFRESH_H(val) do { \
        const int v_ = (int)__builtin_bit_cast(unsigned short, (_Float16)(val)); \
        const int t_ = __builtin_amdgcn_update_dpp(0, v_, 0x101, 0xf, 0xf, true); \
        const int pk_ = (t_ << 16) | (v_ & 0xffff); \
        H0=RDL(0);  H1=RDL(2);  H2=RDL(4);  H3=RDL(6);  H4=RDL(8); \
        H5=RDL(10); H6=RDL(12); H7=RDL(14); H8=RDL(16); H9=RDL(18); \
        H10=RDL(20); H11=RDL(22); H12=RDL(24); H13=RDL(26); H14=RDL(28); \
        H15=RDL(30); H16=RDL(32); H17=RDL(34); H18=RDL(36); H19=RDL(38); \
} while (0)
        REFRESH_H(h);

        struct G3 { __half r, z, n; };
        auto ldg3 = [&](int sc) -> G3 {
            const int scc = max(0, min(sc, sEnd - 1));   // address-safe clamp
            const int tl = dir ? (TC - 1 - scc) : scc;
            const __half* gp = gxR + (gxRow + tl) * GG;
            G3 g; g.r = gp[j]; g.z = gp[HH + j]; g.n = gp[2*HH + j];
            return g;
        };
#define SL(V,i) __builtin_shufflevector(V, V, 2*(i), 2*(i)+1)
#define DOTQ(Rq,Zq,Nq, A,B,C,D) \
        r0 = fdot2_(SL(Rq,0), (A), r0); \
        z0 = fdot2_(SL(Zq,0), (A), z0); \
        n0 = fdot2_(SL(Nq,0), (A), n0); \
        r1 = fdot2_(SL(Rq,1), (B), r1); \
        z1 = fdot2_(SL(Zq,1), (B), z1); \
        n1 = fdot2_(SL(Nq,1), (B), n1); \
        r0 = fdot2_(SL(Rq,2), (C), r0); \
        z0 = fdot2_(SL(Zq,2), (C), z0); \
        n0 = fdot2_(SL(Nq,2), (C), n0); \
        r1 = fdot2_(SL(Rq,3), (D), r1); \
        z1 = fdot2_(SL(Zq,3), (D), z1); \
        n1 = fdot2_(SL(Nq,3), (D), n1);

        constexpr int PF = 4;   // prefetch depth
        auto step = [&](int s, G3& g, bool pf) {
            G3 nx;
            if (pf) nx = ldg3(s + PF);          // clamped inside ldg3
            const int tloc = dir ? (TC - 1 - s) : s;
            float r0 = br, r1 = 0.f, z0 = bz, z1 = 0.f, n0 = bn, n1 = 0.f;
            DOTQ(R0,Z0,N0, H0,H1,H2,H3)
            DOTQ(R1,Z1,N1, H4,H5,H6,H7)
            DOTQ(R2,Z2,N2, H8,H9,H10,H11)
            DOTQ(R3,Z3,N3, H12,H13,H14,H15)
            DOTQ(R4,Z4,N4, H16,H17,H18,H19)
            const float rr = sigmoid_(__half2float(g.r) + r0 + r1);
            const float zz = sigmoid_(__half2float(g.z) + z0 + z1);
            const float nn = tanhfast_(__half2float(g.n) + rr * (n0 + n1));
            const float hn = (1.0f - zz) * nn + zz * h;
            h = hn;                    // all executed steps are valid
            REFRESH_H(hn);             // register broadcast for next step
            if (GATHER) {  // layer 0: materialize out0 fp16 (valid t only)
                const int t = tbase + tloc;
                out0[((size_t)b * TT + t) * X1S + dir*HH + j] = __float2half(hn);
            } else {       // layer 1: fused pooling (valid t only)
                psum += hn;
                pmax = fmaxf(pmax, hn);
            }
            if (pf) g = nx;
        };

        G3 q0 = {}, q1 = {}, q2 = {}, q3 = {};
        if (sBeg < sEnd) {
            q0 = ldg3(sBeg);
            q1 = ldg3(sBeg + 1);
            q2 = ldg3(sBeg + 2);
            q3 = ldg3(sBeg + 3);
        }
        int s = sBeg;
        for (; s + PF <= sEnd; s += PF) {
            step(s + 0, q0, true);
            step(s + 1, q1, true);
            step(s + 2, q2, true);
            step(s + 3, q3, true);
        }
        if (s     < sEnd) step(s,     q0, false);
        if (s + 1 < sEnd) step(s + 1, q1, false);
        if (s + 2 < sEnd) step(s + 2, q2, false);

        hcar[(size_t)(dir * BB + b) * HH + j] = h;
        const int layer = GATHER ? 0 : 1;
        if (cs == NC - 1)
            hlast[((size_t)(layer * 2 + dir) * BB + b) * HH + j] = h;
        if (!GATHER) {
            const size_t pi = (size_t)b * (2*HH) + dir*HH + j;
            if (cs == 0) { sumb[pi] = psum;  maxb[pi] = pmax; }
            else         { sumb[pi] += psum; maxb[pi] = fmaxf(maxb[pi], pmax); }
        }
        return;
    }

    // ============ gemm (MFMA f16, B straight from L2, no LDS) ============
    __builtin_amdgcn_s_setprio(0);
    const int gid = blockIdx.x - nScan;
    const int b   = gid & (BB - 1);
    const int dir = gid >> 9;
    const int chunk = dir ? (NC - 1 - cg) : cg;
    const int tbase = chunk * TC;
    if (tbase >= lens[b]) return;   // tile fully past len: gx never read
    const float* bias = dir ? bb : bf;
    const _Float16* Wg = Wt + (size_t)dir * (KS * 8 * 64 * 8);

    // A gather: lane l -> row = l&15 of wave's 16-row stripe, k-chunk (l>>4)*8
    const int w = tid >> 6, l = tid & 63;
    const int row = l & 15, kq = l >> 4;
    const int t0 = tbase + w * 16 + row;
    h8_t A[4];
    if (GATHER) {
        const int tok = text[b * TT + t0];
        const _Float16* ap = (const _Float16*)emb16 + (size_t)tok * 128 + kq * 8;
        #pragma unroll
        for (int ks = 0; ks < KS; ++ks) A[ks] = *(const h8_t*)(ap + ks * 32);
    } else {
        const _Float16* ap = (const _Float16*)Xh + ((size_t)b * TT + t0) * X1S + kq * 8;
        #pragma unroll
        for (int ks = 0; ks < KS; ++ks) A[ks] = *(const h8_t*)(ap + ks * 32);
    }

    f4_t acc[8] = {};
    #pragma unroll
    for (int ks = 0; ks < KS; ++ks)
        #pragma unroll
        for (int f = 0; f < 8; ++f) {
            const h8_t Bf = *(const h8_t*)(Wg + ((size_t)(ks * 8 + f) * 64 + l) * 8);
            acc[f] = __builtin_amdgcn_mfma_f32_16x16x32_f16(A[ks], Bf, acc[f], 0, 0, 0);
        }

    // epilogue: D[m=(l>>4)*4+reg][n=l&15]; per-element fp16 stores
    const size_t rowB = ((size_t)dir * BB + b) * TC;
    const int gb = l & 15, rq = l >> 4;
    #pragma unroll
    for (int f = 0; f < 8; ++f) {
        const int gate = f * 16 + gb;
        if (gate < GG) {
            const float bv = bias[gate];
            #pragma unroll
            for (int r = 0; r < 4; ++r) {
                const int tloc = w * 16 + rq * 4 + r;
                gxW[(rowB + tloc) * GG + gate] = __float2half(acc[f][r] + bv);
            }
        }
    }
}

// Precompute fp16 tables:
//  emb16 [50000][128] zero-padded; Wt16 = exact B-fragment images:
//  L0 [dir][ks<4][f<8][l<64][i<8], L1 [dir][ks<3][f<8][l<64][i<8];
//  Whh16 fp16 row-major [lay*2+dir][120][40]; plus zero out0 pad columns.
#define NE2 (50000 * 64)        // h2 units of padded emb16
#define NW0 (2*4*8*64)          // 4096 h8 units
#define NW1 (2*3*8*64)          // 3072 h8 units
#define NHH (4*120*20)          // 9600 h2 units
#define NP0 (BB*TT*8)           // h2 units of out0 pad (16 halfs/row)
__global__ __launch_bounds__(256) void prep_kernel(
    const float* __restrict__ emb,
    const float* __restrict__ Wih0f, const float* __restrict__ Wih0b,
    const float* __restrict__ Wih1f, const float* __restrict__ Wih1b,
    const float* __restrict__ Whh0f, const float* __restrict__ Whh0b,
    const float* __restrict__ Whh1f, const float* __restrict__ Whh1b,
    __half* __restrict__ emb16, _Float16* __restrict__ Wt16,
    _Float16* __restrict__ Whh16, __half* __restrict__ out0)
{
    const int gid = blockIdx.x * 256 + threadIdx.x;
    if (gid < NE2) {
        const int v = gid >> 6, q2 = gid & 63;
        const int k0 = q2 * 2;
        float x0 = 0.f, x1 = 0.f;
        if (k0 < EE) { x0 = emb[(size_t)v * EE + k0]; x1 = emb[(size_t)v * EE + k0 + 1]; }
        ((h2_t*)emb16)[(size_t)v * 64 + q2] = pack2_(x0, x1);
        return;
    }
    int e = gid - NE2;
    if (e < NP0) {              // zero out0 pad columns (halfs 80..95 per row)
        const int row = e >> 3, q = e & 7;
        ((h2_t*)out0)[(size_t)row * 48 + 40 + q] = pack2_(0.f, 0.f);
        return;
    }
    e -= NP0;
    if (e < NW0) {              // layer0 B-fragments, K=100 (pad 128)
        const int l = e & 63, f = (e >> 6) & 7, ks = (e >> 9) & 3, dir = e >> 11;
        const float* W = dir ? Wih0b : Wih0f;
        const int col = f * 16 + (l & 15);
        const int kb  = ks * 32 + (l >> 4) * 8;
        _Float16* dst = Wt16 + (size_t)e * 8;
        #pragma unroll
        for (int i = 0; i < 8; ++i) {
            const int k = kb + i;
            dst[i] = (_Float16)((col < GG && k < EE) ? W[(size_t)col * EE + k] : 0.f);
        }
        return;
    }
    e -= NW0;
    if (e < NW1) {              // layer1 B-fragments, K=80 (pad 96)
        const int l = e & 63, f = (e >> 6) & 7;
        const int t = e >> 9;               // 0..5 = dir*3 + ks
        const int ks = t % 3, dir = t / 3;
        const float* W = dir ? Wih1b : Wih1f;
        const int col = f * 16 + (l & 15);
        const int kb  = ks * 32 + (l >> 4) * 8;
        _Float16* dst = Wt16 + (size_t)(NW0 + e) * 8;
        #pragma unroll
        for (int i = 0; i < 8; ++i) {
            const int k = kb + i;
            dst[i] = (_Float16)((col < GG && k < 2*HH) ? W[(size_t)col * (2*HH) + k] : 0.f);
        }
        return;
    }
    e -= NW1;
    if (e < NHH) {              // Whh fp16, 4 x [120][40]
        const int ld = e / 2400, rem = e - ld * 2400;
        const int row2 = rem / 20, kk = rem - row2 * 20;
        const float* W = (ld == 0) ? Whh0f : (ld == 1) ? Whh0b
                       : (ld == 2) ? Whh1f : Whh1b;
        ((h2_t*)Whh16)[e] = pack2_(W[row2*HH + 2*kk], W[row2*HH + 2*kk + 1]);
    }
}

// pool_cat = [hb1, hf1, hb0, hf0, avg(80), max(80)] -> fc1(128) -> lrelu -> fc2(1)
__global__ __launch_bounds__(128) void fc_kernel(
    const float* __restrict__ hlast, const float* __restrict__ sumb,
    const float* __restrict__ maxb, const int* __restrict__ lens,
    const float* __restrict__ fc1W, const float* __restrict__ fc1b,
    const float* __restrict__ fc2W, const float* __restrict__ fc2b,
    float* __restrict__ out)
{
    __shared__ float pool[8 * HH];
    __shared__ float red[128];
    const int b = blockIdx.x, tid = threadIdx.x;
    if (tid < HH) {
        pool[tid]        = hlast[(size_t)(3*BB + b) * HH + tid]; // hb1
        pool[HH + tid]   = hlast[(size_t)(2*BB + b) * HH + tid]; // hf1
        pool[2*HH + tid] = hlast[(size_t)(1*BB + b) * HH + tid]; // hb0
        pool[3*HH + tid] = hlast[(size_t)(0*BB + b) * HH + tid]; // hf0
    }
    const float invLen = 1.0f / (float)lens[b];
    if (tid < 2*HH) {
        pool[4*HH + tid] = sumb[(size_t)b * 2*HH + tid] * invLen;
        pool[6*HH + tid] = maxb[(size_t)b * 2*HH + tid];
    }
    __syncthreads();
    float acc = fc1b[tid];
    for (int k = 0; k < 8*HH; ++k)
        acc = fmaf(pool[k], fc1W[(size_t)tid * (8*HH) + k], acc);
    float v = (acc >= 0.0f) ? acc : 0.01f * acc;
    red[tid] = v * fc2W[tid];
    __syncthreads();
    for (int s = 64; s > 0; s >>= 1) {
        if (tid < s) red[tid] += red[tid + s];
        __syncthreads();
    }
    if (tid == 0) out[b] = red[0] + fc2b[0];
}

extern "C" void kernel_launch(void* const* d_in, const int* in_sizes, int n_in,
                              void* d_out, int out_size, void* d_ws, size_t ws_size,
                              hipStream_t stream) {
    const int*   text  = (const int*)d_in[0];
    const int*   lens  = (const int*)d_in[1];
    const float* emb   = (const float*)d_in[2];
    const float* Wih0f = (const float*)d_in[3];
    const float* Whh0f = (const float*)d_in[4];
    const float* bih0f = (const float*)d_in[5];
    const float* bhh0f = (const float*)d_in[6];
    const float* Wih0b = (const float*)d_in[7];
    const float* Whh0b = (const float*)d_in[8];
    const float* bih0b = (const float*)d_in[9];
    const float* bhh0b = (const float*)d_in[10];
    const float* Wih1f = (const float*)d_in[11];
    const float* Whh1f = (const float*)d_in[12];
    const float* bih1f = (const float*)d_in[13];
    const float* bhh1f = (const float*)d_in[14];
    const float* Wih1b = (const float*)d_in[15];
    const float* Whh1b = (const float*)d_in[16];
    const float* bih1b = (const float*)d_in[17];
    const float* bhh1b = (const float*)d_in[18];
    const float* fc1W  = (const float*)d_in[19];
    const float* fc1b  = (const float*)d_in[20];
    const float* fc2W  = (const float*)d_in[21];
    const float* fc2b  = (const float*)d_in[22];
    float* out = (float*)d_out;

    // ws: gx dbuf fp16 | out0 fp16 (stride 96) | small | fp16 tables
    char* p = (char*)d_ws;
    const size_t gxB = (size_t)2 * BB * TC * GG * sizeof(__half);
    __half* gxb0  = (__half*)p;  p += gxB;
    __half* gxb1  = (__half*)p;  p += gxB;
    __half* out0  = (__half*)p;  p += (size_t)BB * TT * X1S * sizeof(__half);
    float*  hcar  = (float*)p;   p += (size_t)2 * BB * HH * sizeof(float);
    float*  hlast = (float*)p;   p += (size_t)4 * BB * HH * sizeof(float);
    float*  sumb  = (float*)p;   p += (size_t)BB * 2 * HH * sizeof(float);
    float*  maxb  = (float*)p;   p += (size_t)BB * 2 * HH * sizeof(float);
    __half*    emb16 = (__half*)p;    p += (size_t)50000 * 128 * sizeof(__half);
    _Float16*  Wt16  = (_Float16*)p;  p += (size_t)(NW0 + NW1) * 8 * sizeof(_Float16);
    _Float16*  Whh16 = (_Float16*)p;
    __half* gxb[2] = { gxb0, gxb1 };

    const int NG = BB * 2;       // 1024 gemm blocks (b, dir)
    const int NS = 256;          // 1024 chains / 4 waves per block

    // ---- precompute fp16 tables + out0 pad zeroing ----
    {
        const int total = NE2 + NP0 + NW0 + NW1 + NHH;
        prep_kernel<<<(total + 255) / 256, 256, 0, stream>>>(
            emb, Wih0f, Wih0b, Wih1f, Wih1b, Whh0f, Whh0b, Whh1f, Whh1b,
            emb16, Wt16, Whh16, out0);
    }

    // ---- layer 0 ----
    fused_kernel<EE, true><<<NG, 256, 0, stream>>>(0, 0, 0,
        text, emb16, nullptr, Wt16, bih0f, bih0b,
        gxb[0], gxb[0], Whh16, bhh0f, bhh0b,
        lens, out0, hcar, hlast, sumb, maxb);
    for (int ci = 1; ci < NC; ++ci)
        fused_kernel<EE, true><<<NS + NG, 256, 0, stream>>>(ci, ci - 1, NS,
            text, emb16, nullptr, Wt16, bih0f, bih0b,
            gxb[ci & 1], gxb[(ci - 1) & 1], Whh16, bhh0f, bhh0b,
            lens, out0, hcar, hlast, sumb, maxb);
    fused_kernel<EE, true><<<NS, 256, 0, stream>>>(0, NC - 1, NS,
        text, emb16, nullptr, Wt16, bih0f, bih0b,
        gxb[0], gxb[(NC - 1) & 1], Whh16, bhh0f, bhh0b,
        lens, out0, hcar, hlast, sumb, maxb);

    // ---- layer 1 ----
    fused_kernel<2*HH, false><<<NG, 256, 0, stream>>>(0, 0, 0,
        text, emb16, out0, Wt16 + (size_t)NW0 * 8, bih1f, bih1b,
        gxb[0], gxb[0], Whh16 + 9600, bhh1f, bhh1b,
        lens, out0, hcar, hlast, sumb, maxb);
    for (int ci = 1; ci < NC; ++ci)
        fused_kernel<2*HH, false><<<NS + NG, 256, 0, stream>>>(ci, ci - 1, NS,
            text, emb16, out0, Wt16 + (size_t)NW0 * 8, bih1f, bih1b,
            gxb[ci & 1], gxb[(ci - 1) & 1], Whh16 + 9600, bhh1f, bhh1b,
            lens, out0, hcar, hlast, sumb, maxb);
    fused_kernel<2*HH, false><<<NS, 256, 0, stream>>>(0, NC - 1, NS,
        text, emb16, out0, Wt16 + (size_t)NW0 * 8, bih1f, bih1b,
        gxb[0], gxb[(NC - 1) & 1], Whh16 + 9600, bhh1f, bhh1b,
        lens, out0, hcar, hlast, sumb, maxb);

    // ---- head ----
    fc_kernel<<<BB, 128, 0, stream>>>(hlast, sumb, maxb, lens,
        fc1W, fc1b, fc2W, fc2b, out);
}

// Round 9
// 499.105 us; speedup vs baseline: 1.6533x; 1.0844x over previous
//
#include <hip/hip_runtime.h>
#include <hip/hip_fp16.h>

#define BB 512
#define TT 512
#define EE 100
#define HH 40
#define GG 120   // 3*HH
#define TC 256   // timesteps per chunk (r9: 64 -> 256, launch-overhead cut)
#define NC 2     // chunks
#define NT (TC/64)  // 64-row GEMM tiles per chunk
#define X1S 96   // layer-1 input row stride (80 valid + 16 pad, 3 k-steps of 32)

typedef _Float16 h2_t __attribute__((ext_vector_type(2)));
typedef _Float16 h8_t __attribute__((ext_vector_type(8)));
typedef float    f4_t __attribute__((ext_vector_type(4)));

__device__ __forceinline__ float fdot2_(h2_t a, h2_t b, float c) {
    return __builtin_amdgcn_fdot2(a, b, c, false);
}
__device__ __forceinline__ h2_t pack2_(float x, float y) {
    h2_t r; r[0] = (_Float16)x; r[1] = (_Float16)y; return r;
}
__device__ __forceinline__ float sigmoid_(float x) {
    return __builtin_amdgcn_rcpf(1.0f + __expf(-x));
}
__device__ __forceinline__ float tanhfast_(float x) {
    return 1.0f - 2.0f * __builtin_amdgcn_rcpf(__expf(2.0f * x) + 1.0f);
}

// Round-18 model: r8 (541us, pass) showed the register h-broadcast only bought
// ~2us/dispatch => the ~300cy LDS round-trip was NOT the step pole. Remaining
// suspects: (1) launch overhead (~8-10us x 20 serial launches ~ 160us) and
// (2) scan step-time still ~1000cy (unmeasurable: scan dispatches hidden
// below the 42us workspace-fill kernels in top-5).
// This round: NC 8->2 (TC=256). Total scan steps invariant, so:
//  - if overhead dominates: 20 -> 8 launches saves ~100us;
//  - the pure-scan tail dispatch now runs 256 steps => tops the profile and
//    directly measures step time (30us if ~280cy, 117us if ~1100cy).
// GEMM: tile index in gid (NT=4 tiles of 64 rows/chunk), NG=4096.
// ws: gx dbuf 2x63MB, total ~190MB < 256MiB (fills show ws = 256MiB).
template<int K, bool GATHER>
__global__ __launch_bounds__(256, 1) void fused_kernel(
    const int cg, const int cs, const int nScan,
    const int* __restrict__ text, const __half* __restrict__ emb16,
    const __half* __restrict__ Xh,
    const _Float16* __restrict__ Wt,
    const float* __restrict__ bf, const float* __restrict__ bb,
    __half* __restrict__ gxW, const __half* __restrict__ gxR,
    const _Float16* __restrict__ WhhL,
    const float* __restrict__ bhhF, const float* __restrict__ bhhB,
    const int* __restrict__ lens,
    __half* __restrict__ out0,
    float* __restrict__ hcar, float* __restrict__ hlast,
    float* __restrict__ sumb, float* __restrict__ maxb)
{
    constexpr int KS = (K == 100) ? 4 : 3;       // k-steps of 32
    const int tid = threadIdx.x;

    if ((int)blockIdx.x < nScan) {
        // ============ scan: one wave = one (batch,dir) chain ============
        __builtin_amdgcn_s_setprio(3);
        const int wave = tid >> 6, j = tid & 63;
        if (j >= HH) return;
        const int chain = blockIdx.x * 4 + wave;   // 0..1023
        const int dir = chain >> 9;
        const int b   = chain & (BB - 1);
        const float* bhh = dir ? bhhB : bhhF;

        // Whh rows {j,40+j,80+j} fp16 in 15 h8 registers, forced resident
        h8_t R0,R1,R2,R3,R4, Z0,Z1,Z2,Z3,Z4, N0,N1,N2,N3,N4;
        {
            const _Float16* wr = WhhL + (size_t)dir * 4800;
            const h8_t* pr = (const h8_t*)(wr + (size_t)j * 40);
            const h8_t* pz = (const h8_t*)(wr + (size_t)(40 + j) * 40);
            const h8_t* pn = (const h8_t*)(wr + (size_t)(80 + j) * 40);
            R0=pr[0]; R1=pr[1]; R2=pr[2]; R3=pr[3]; R4=pr[4];
            Z0=pz[0]; Z1=pz[1]; Z2=pz[2]; Z3=pz[3]; Z4=pz[4];
            N0=pn[0]; N1=pn[1]; N2=pn[2]; N3=pn[3]; N4=pn[4];
        }
        asm volatile("" : "+v"(R0),"+v"(R1),"+v"(R2),"+v"(R3),"+v"(R4),
                          "+v"(Z0),"+v"(Z1),"+v"(Z2),"+v"(Z3),"+v"(Z4),
                          "+v"(N0),"+v"(N1),"+v"(N2),"+v"(N3),"+v"(N4));
        const float br = bhh[j], bz = bhh[HH + j], bn = bhh[2*HH + j];
        const int len = lens[b];
        const int chunk = dir ? (NC - 1 - cs) : cs;
        const int tbase = chunk * TC;

        // executed step range: all executed steps have t < len
        int sBeg, sEnd;
        if (dir == 0) { sBeg = 0; sEnd = min(TC, max(0, len - tbase)); }
        else          { sBeg = max(0, tbase + TC - len); sEnd = TC; }

        float h = (cs == 0) ? 0.0f : hcar[(size_t)(dir * BB + b) * HH + j];
        float psum = 0.0f, pmax = -3.4e38f;
        const size_t gxRow = ((size_t)dir * BB + b) * TC;

        // 20 uniform h2 broadcast registers (live in SGPRs via readlane)
        h2_t H0{},H1{},H2{},H3{},H4{},H5{},H6{},H7{},H8{},H9{},
             H10{},H11{},H12{},H13{},H14{},H15{},H16{},H17{},H18{},H19{};
#define RDL(L) __builtin_bit_cast(h2_t, __builtin_amdgcn_readlane(pk_, (L)))
#define REFRESH_H(val) do { \
        const int v_ = (int)__builtin_bit_cast(unsigned short, (_Float16)(val)); \
        const int t_ = __builtin_amdgcn_update_dpp(0, v_, 0x101, 0xf, 0xf, true); \
        const int pk_ = (t_ << 16) | (v_ & 0xffff); \
        H0=RDL(0);  H1=RDL(2);  H2=RDL(4);  H3=RDL(6);  H4=RDL(8); \
        H5=RDL(10); H6=RDL(12); H7=RDL(14); H8=RDL(16); H9=RDL(18); \
        H10=RDL(20); H11=RDL(22); H12=RDL(24); H13=RDL(26); H14=RDL(28); \
        H15=RDL(30); H16=RDL(32); H17=RDL(34); H18=RDL(36); H19=RDL(38); \
} while (0)
        REFRESH_H(h);

        struct G3 { __half r, z, n; };
        auto ldg3 = [&](int sc) -> G3 {
            const int scc = max(0, min(sc, sEnd - 1));   // address-safe clamp
            const int tl = dir ? (TC - 1 - scc) : scc;
            const __half* gp = gxR + (gxRow + tl) * GG;
            G3 g; g.r = gp[j]; g.z = gp[HH + j]; g.n = gp[2*HH + j];
            return g;
        };
#define SL(V,i) __builtin_shufflevector(V, V, 2*(i), 2*(i)+1)
#define DOTQ(Rq,Zq,Nq, A,B,C,D) \
        r0 = fdot2_(SL(Rq,0), (A), r0); \
        z0 = fdot2_(SL(Zq,0), (A), z0); \
        n0 = fdot2_(SL(Nq,0), (A), n0); \
        r1 = fdot2_(SL(Rq,1), (B), r1); \
        z1 = fdot2_(SL(Zq,1), (B), z1); \
        n1 = fdot2_(SL(Nq,1), (B), n1); \
        r0 = fdot2_(SL(Rq,2), (C), r0); \
        z0 = fdot2_(SL(Zq,2), (C), z0); \
        n0 = fdot2_(SL(Nq,2), (C), n0); \
        r1 = fdot2_(SL(Rq,3), (D), r1); \
        z1 = fdot2_(SL(Zq,3), (D), z1); \
        n1 = fdot2_(SL(Nq,3), (D), n1);

        constexpr int PF = 4;   // prefetch depth
        auto step = [&](int s, G3& g, bool pf) {
            G3 nx;
            if (pf) nx = ldg3(s + PF);          // clamped inside ldg3
            const int tloc = dir ? (TC - 1 - s) : s;
            float r0 = br, r1 = 0.f, z0 = bz, z1 = 0.f, n0 = bn, n1 = 0.f;
            DOTQ(R0,Z0,N0, H0,H1,H2,H3)
            DOTQ(R1,Z1,N1, H4,H5,H6,H7)
            DOTQ(R2,Z2,N2, H8,H9,H10,H11)
            DOTQ(R3,Z3,N3, H12,H13,H14,H15)
            DOTQ(R4,Z4,N4, H16,H17,H18,H19)
            const float rr = sigmoid_(__half2float(g.r) + r0 + r1);
            const float zz = sigmoid_(__half2float(g.z) + z0 + z1);
            const float nn = tanhfast_(__half2float(g.n) + rr * (n0 + n1));
            const float hn = (1.0f - zz) * nn + zz * h;
            h = hn;                    // all executed steps are valid
            REFRESH_H(hn);             // register broadcast for next step
            if (GATHER) {  // layer 0: materialize out0 fp16 (valid t only)
                const int t = tbase + tloc;
                out0[((size_t)b * TT + t) * X1S + dir*HH + j] = __float2half(hn);
            } else {       // layer 1: fused pooling (valid t only)
                psum += hn;
                pmax = fmaxf(pmax, hn);
            }
            if (pf) g = nx;
        };

        G3 q0 = {}, q1 = {}, q2 = {}, q3 = {};
        if (sBeg < sEnd) {
            q0 = ldg3(sBeg);
            q1 = ldg3(sBeg + 1);
            q2 = ldg3(sBeg + 2);
            q3 = ldg3(sBeg + 3);
        }
        int s = sBeg;
        for (; s + PF <= sEnd; s += PF) {
            step(s + 0, q0, true);
            step(s + 1, q1, true);
            step(s + 2, q2, true);
            step(s + 3, q3, true);
        }
        if (s     < sEnd) step(s,     q0, false);
        if (s + 1 < sEnd) step(s + 1, q1, false);
        if (s + 2 < sEnd) step(s + 2, q2, false);

        hcar[(size_t)(dir * BB + b) * HH + j] = h;
        const int layer = GATHER ? 0 : 1;
        if (cs == NC - 1)
            hlast[((size_t)(layer * 2 + dir) * BB + b) * HH + j] = h;
        if (!GATHER) {
            const size_t pi = (size_t)b * (2*HH) + dir*HH + j;
            if (cs == 0) { sumb[pi] = psum;  maxb[pi] = pmax; }
            else         { sumb[pi] += psum; maxb[pi] = fmaxf(maxb[pi], pmax); }
        }
        return;
    }

    // ============ gemm (MFMA f16, B straight from L2, no LDS) ============
    __builtin_amdgcn_s_setprio(0);
    const int gid = blockIdx.x - nScan;
    const int b    = gid & (BB - 1);
    const int tile = (gid >> 9) & (NT - 1);
    const int dir  = gid >> (9 + 2);             // NT=4 -> 2 bits
    const int chunk = dir ? (NC - 1 - cg) : cg;
    const int tbase = chunk * TC + tile * 64;
    if (tbase >= lens[b]) return;   // tile fully past len: gx never read
    const float* bias = dir ? bb : bf;
    const _Float16* Wg = Wt + (size_t)dir * (KS * 8 * 64 * 8);

    // A gather: lane l -> row = l&15 of wave's 16-row stripe, k-chunk (l>>4)*8
    const int w = tid >> 6, l = tid & 63;
    const int row = l & 15, kq = l >> 4;
    const int t0 = tbase + w * 16 + row;
    h8_t A[4];
    if (GATHER) {
        const int tok = text[b * TT + t0];
        const _Float16* ap = (const _Float16*)emb16 + (size_t)tok * 128 + kq * 8;
        #pragma unroll
        for (int ks = 0; ks < KS; ++ks) A[ks] = *(const h8_t*)(ap + ks * 32);
    } else {
        const _Float16* ap = (const _Float16*)Xh + ((size_t)b * TT + t0) * X1S + kq * 8;
        #pragma unroll
        for (int ks = 0; ks < KS; ++ks) A[ks] = *(const h8_t*)(ap + ks * 32);
    }

    f4_t acc[8] = {};
    #pragma unroll
    for (int ks = 0; ks < KS; ++ks)
        #pragma unroll
        for (int f = 0; f < 8; ++f) {
            const h8_t Bf = *(const h8_t*)(Wg + ((size_t)(ks * 8 + f) * 64 + l) * 8);
            acc[f] = __builtin_amdgcn_mfma_f32_16x16x32_f16(A[ks], Bf, acc[f], 0, 0, 0);
        }

    // epilogue: D[m=(l>>4)*4+reg][n=l&15]; per-element fp16 stores
    const size_t rowB = ((size_t)dir * BB + b) * TC;
    const int gb = l & 15, rq = l >> 4;
    #pragma unroll
    for (int f = 0; f < 8; ++f) {
        const int gate = f * 16 + gb;
        if (gate < GG) {
            const float bv = bias[gate];
            #pragma unroll
            for (int r = 0; r < 4; ++r) {
                const int tloc = tile * 64 + w * 16 + rq * 4 + r;
                gxW[(rowB + tloc) * GG + gate] = __float2half(acc[f][r] + bv);
            }
        }
    }
}

// Precompute fp16 tables:
//  emb16 [50000][128] zero-padded; Wt16 = exact B-fragment images:
//  L0 [dir][ks<4][f<8][l<64][i<8], L1 [dir][ks<3][f<8][l<64][i<8];
//  Whh16 fp16 row-major [lay*2+dir][120][40]; plus zero out0 pad columns.
#define NE2 (50000 * 64)        // h2 units of padded emb16
#define NW0 (2*4*8*64)          // 4096 h8 units
#define NW1 (2*3*8*64)          // 3072 h8 units
#define NHH (4*120*20)          // 9600 h2 units
#define NP0 (BB*TT*8)           // h2 units of out0 pad (16 halfs/row)
__global__ __launch_bounds__(256) void prep_kernel(
    const float* __restrict__ emb,
    const float* __restrict__ Wih0f, const float* __restrict__ Wih0b,
    const float* __restrict__ Wih1f, const float* __restrict__ Wih1b,
    const float* __restrict__ Whh0f, const float* __restrict__ Whh0b,
    const float* __restrict__ Whh1f, const float* __restrict__ Whh1b,
    __half* __restrict__ emb16, _Float16* __restrict__ Wt16,
    _Float16* __restrict__ Whh16, __half* __restrict__ out0)
{
    const int gid = blockIdx.x * 256 + threadIdx.x;
    if (gid < NE2) {
        const int v = gid >> 6, q2 = gid & 63;
        const int k0 = q2 * 2;
        float x0 = 0.f, x1 = 0.f;
        if (k0 < EE) { x0 = emb[(size_t)v * EE + k0]; x1 = emb[(size_t)v * EE + k0 + 1]; }
        ((h2_t*)emb16)[(size_t)v * 64 + q2] = pack2_(x0, x1);
        return;
    }
    int e = gid - NE2;
    if (e < NP0) {              // zero out0 pad columns (halfs 80..95 per row)
        const int row = e >> 3, q = e & 7;
        ((h2_t*)out0)[(size_t)row * 48 + 40 + q] = pack2_(0.f, 0.f);
        return;
    }
    e -= NP0;
    if (e < NW0) {              // layer0 B-fragments, K=100 (pad 128)
        const int l = e & 63, f = (e >> 6) & 7, ks = (e >> 9) & 3, dir = e >> 11;
        const float* W = dir ? Wih0b : Wih0f;
        const int col = f * 16 + (l & 15);
        const int kb  = ks * 32 + (l >> 4) * 8;
        _Float16* dst = Wt16 + (size_t)e * 8;
        #pragma unroll
        for (int i = 0; i < 8; ++i) {
            const int k = kb + i;
            dst[i] = (_Float16)((col < GG && k < EE) ? W[(size_t)col * EE + k] : 0.f);
        }
        return;
    }
    e -= NW0;
    if (e < NW1) {              // layer1 B-fragments, K=80 (pad 96)
        const int l = e & 63, f = (e >> 6) & 7;
        const int t = e >> 9;               // 0..5 = dir*3 + ks
        const int ks = t % 3, dir = t / 3;
        const float* W = dir ? Wih1b : Wih1f;
        const int col = f * 16 + (l & 15);
        const int kb  = ks * 32 + (l >> 4) * 8;
        _Float16* dst = Wt16 + (size_t)(NW0 + e) * 8;
        #pragma unroll
        for (int i = 0; i < 8; ++i) {
            const int k = kb + i;
            dst[i] = (_Float16)((col < GG && k < 2*HH) ? W[(size_t)col * (2*HH) + k] : 0.f);
        }
        return;
    }
    e -= NW1;
    if (e < NHH) {              // Whh fp16, 4 x [120][40]
        const int ld = e / 2400, rem = e - ld * 2400;
        const int row2 = rem / 20, kk = rem - row2 * 20;
        const float* W = (ld == 0) ? Whh0f : (ld == 1) ? Whh0b
                       : (ld == 2) ? Whh1f : Whh1b;
        ((h2_t*)Whh16)[e] = pack2_(W[row2*HH + 2*kk], W[row2*HH + 2*kk + 1]);
    }
}

// pool_cat = [hb1, hf1, hb0, hf0, avg(80), max(80)] -> fc1(128) -> lrelu -> fc2(1)
__global__ __launch_bounds__(128) void fc_kernel(
    const float* __restrict__ hlast, const float* __restrict__ sumb,
    const float* __restrict__ maxb, const int* __restrict__ lens,
    const float* __restrict__ fc1W, const float* __restrict__ fc1b,
    const float* __restrict__ fc2W, const float* __restrict__ fc2b,
    float* __restrict__ out)
{
    __shared__ float pool[8 * HH];
    __shared__ float red[128];
    const int b = blockIdx.x, tid = threadIdx.x;
    if (tid < HH) {
        pool[tid]        = hlast[(size_t)(3*BB + b) * HH + tid]; // hb1
        pool[HH + tid]   = hlast[(size_t)(2*BB + b) * HH + tid]; // hf1
        pool[2*HH + tid] = hlast[(size_t)(1*BB + b) * HH + tid]; // hb0
        pool[3*HH + tid] = hlast[(size_t)(0*BB + b) * HH + tid]; // hf0
    }
    const float invLen = 1.0f / (float)lens[b];
    if (tid < 2*HH) {
        pool[4*HH + tid] = sumb[(size_t)b * 2*HH + tid] * invLen;
        pool[6*HH + tid] = maxb[(size_t)b * 2*HH + tid];
    }
    __syncthreads();
    float acc = fc1b[tid];
    for (int k = 0; k < 8*HH; ++k)
        acc = fmaf(pool[k], fc1W[(size_t)tid * (8*HH) + k], acc);
    float v = (acc >= 0.0f) ? acc : 0.01f * acc;
    red[tid] = v * fc2W[tid];
    __syncthreads();
    for (int s = 64; s > 0; s >>= 1) {
        if (tid < s) red[tid] += red[tid + s];
        __syncthreads();
    }
    if (tid == 0) out[b] = red[0] + fc2b[0];
}

extern "C" void kernel_launch(void* const* d_in, const int* in_sizes, int n_in,
                              void* d_out, int out_size, void* d_ws, size_t ws_size,
                              hipStream_t stream) {
    const int*   text  = (const int*)d_in[0];
    const int*   lens  = (const int*)d_in[1];
    const float* emb   = (const float*)d_in[2];
    const float* Wih0f = (const float*)d_in[3];
    const float* Whh0f = (const float*)d_in[4];
    const float* bih0f = (const float*)d_in[5];
    const float* bhh0f = (const float*)d_in[6];
    const float* Wih0b = (const float*)d_in[7];
    const float* Whh0b = (const float*)d_in[8];
    const float* bih0b = (const float*)d_in[9];
    const float* bhh0b = (const float*)d_in[10];
    const float* Wih1f = (const float*)d_in[11];
    const float* Whh1f = (const float*)d_in[12];
    const float* bih1f = (const float*)d_in[13];
    const float* bhh1f = (const float*)d_in[14];
    const float* Wih1b = (const float*)d_in[15];
    const float* Whh1b = (const float*)d_in[16];
    const float* bih1b = (const float*)d_in[17];
    const float* bhh1b = (const float*)d_in[18];
    const float* fc1W  = (const float*)d_in[19];
    const float* fc1b  = (const float*)d_in[20];
    const float* fc2W  = (const float*)d_in[21];
    const float* fc2b  = (const float*)d_in[22];
    float* out = (float*)d_out;

    // ws: gx dbuf fp16 (2 x 62.9MB) | out0 fp16 (50.3MB) | small | tables
    char* p = (char*)d_ws;
    const size_t gxB = (size_t)2 * BB * TC * GG * sizeof(__half);
    __half* gxb0  = (__half*)p;  p += gxB;
    __half* gxb1  = (__half*)p;  p += gxB;
    __half* out0  = (__half*)p;  p += (size_t)BB * TT * X1S * sizeof(__half);
    float*  hcar  = (float*)p;   p += (size_t)2 * BB * HH * sizeof(float);
    float*  hlast = (float*)p;   p += (size_t)4 * BB * HH * sizeof(float);
    float*  sumb  = (float*)p;   p += (size_t)BB * 2 * HH * sizeof(float);
    float*  maxb  = (float*)p;   p += (size_t)BB * 2 * HH * sizeof(float);
    __half*    emb16 = (__half*)p;    p += (size_t)50000 * 128 * sizeof(__half);
    _Float16*  Wt16  = (_Float16*)p;  p += (size_t)(NW0 + NW1) * 8 * sizeof(_Float16);
    _Float16*  Whh16 = (_Float16*)p;
    __half* gxb[2] = { gxb0, gxb1 };

    const int NG = BB * 2 * NT;  // 4096 gemm blocks (b, tile, dir)
    const int NS = 256;          // 1024 chains / 4 waves per block

    // ---- precompute fp16 tables + out0 pad zeroing ----
    {
        const int total = NE2 + NP0 + NW0 + NW1 + NHH;
        prep_kernel<<<(total + 255) / 256, 256, 0, stream>>>(
            emb, Wih0f, Wih0b, Wih1f, Wih1b, Whh0f, Whh0b, Whh1f, Whh1b,
            emb16, Wt16, Whh16, out0);
    }

    // ---- layer 0 ----
    fused_kernel<EE, true><<<NG, 256, 0, stream>>>(0, 0, 0,
        text, emb16, nullptr, Wt16, bih0f, bih0b,
        gxb[0], gxb[0], Whh16, bhh0f, bhh0b,
        lens, out0, hcar, hlast, sumb, maxb);
    for (int ci = 1; ci < NC; ++ci)
        fused_kernel<EE, true><<<NS + NG, 256, 0, stream>>>(ci, ci - 1, NS,
            text, emb16, nullptr, Wt16, bih0f, bih0b,
            gxb[ci & 1], gxb[(ci - 1) & 1], Whh16, bhh0f, bhh0b,
            lens, out0, hcar, hlast, sumb, maxb);
    fused_kernel<EE, true><<<NS, 256, 0, stream>>>(0, NC - 1, NS,
        text, emb16, nullptr, Wt16, bih0f, bih0b,
        gxb[0], gxb[(NC - 1) & 1], Whh16, bhh0f, bhh0b,
        lens, out0, hcar, hlast, sumb, maxb);

    // ---- layer 1 ----
    fused_kernel<2*HH, false><<<NG, 256, 0, stream>>>(0, 0, 0,
        text, emb16, out0, Wt16 + (size_t)NW0 * 8, bih1f, bih1b,
        gxb[0], gxb[0], Whh16 + 9600, bhh1f, bhh1b,
        lens, out0, hcar, hlast, sumb, maxb);
    for (int ci = 1; ci < NC; ++ci)
        fused_kernel<2*HH, false><<<NS + NG, 256, 0, stream>>>(ci, ci - 1, NS,
            text, emb16, out0, Wt16 + (size_t)NW0 * 8, bih1f, bih1b,
            gxb[ci & 1], gxb[(ci - 1) & 1], Whh16 + 9600, bhh1f, bhh1b,
            lens, out0, hcar, hlast, sumb, maxb);
    fused_kernel<2*HH, false><<<NS, 256, 0, stream>>>(0, NC - 1, NS,
        text, emb16, out0, Wt16 + (size_t)NW0 * 8, bih1f, bih1b,
        gxb[0], gxb[(NC - 1) & 1], Whh16 + 9600, bhh1f, bhh1b,
        lens, out0, hcar, hlast, sumb, maxb);

    // ---- head ----
    fc_kernel<<<BB, 128, 0, stream>>>(hlast, sumb, maxb, lens,
        fc1W, fc1b, fc2W, fc2b, out);
}